// Round 1
// 1421.281 us; speedup vs baseline: 1.3008x; 1.3008x over previous
//
#include <hip/hip_runtime.h>
#include <hip/hip_bf16.h>
#include <math.h>

// ---- types ---------------------------------------------------------------
typedef __bf16 bf16x8 __attribute__((ext_vector_type(8)));  // MFMA A/B frag (4 VGPRs)
typedef __bf16 bf16x4 __attribute__((ext_vector_type(4)));
typedef float  f32x4  __attribute__((ext_vector_type(4)));  // MFMA C/D frag

typedef const __attribute__((address_space(1))) void* gas_ptr;
typedef __attribute__((address_space(3))) void*       las_ptr;

__device__ __forceinline__ void gload_lds16(const void* g, void* l) {
  // async global->LDS, 16B per lane; LDS dest = wave-uniform base + lane*16
  __builtin_amdgcn_global_load_lds((gas_ptr)g, (las_ptr)l, 16, 0, 0);
}
// raw barrier / waits with compiler memory fence (no auto vmcnt(0) drain)
__device__ __forceinline__ void barrier_() { asm volatile("s_barrier" ::: "memory"); }
__device__ __forceinline__ void lgkm0_()   { asm volatile("s_waitcnt lgkmcnt(0)" ::: "memory"); }
__device__ __forceinline__ void vm4_()     { asm volatile("s_waitcnt vmcnt(4)" ::: "memory"); }

// ---- conversion kernels --------------------------------------------------
__global__ void cvt_f32_bf16(const float4* __restrict__ in, bf16x4* __restrict__ out, long n4) {
  long i = (long)blockIdx.x * blockDim.x + threadIdx.x;
  if (i >= n4) return;
  float4 f = in[i];
  bf16x4 o;
  o.x = (__bf16)f.x; o.y = (__bf16)f.y; o.z = (__bf16)f.z; o.w = (__bf16)f.w;
  out[i] = o;
}

__global__ void cvt_i32_bf16(const int4* __restrict__ in, bf16x4* __restrict__ out, long n4) {
  long i = (long)blockIdx.x * blockDim.x + threadIdx.x;
  if (i >= n4) return;
  int4 f = in[i];
  bf16x4 o;
  o.x = (__bf16)(float)f.x; o.y = (__bf16)(float)f.y;
  o.z = (__bf16)(float)f.z; o.w = (__bf16)(float)f.w;
  out[i] = o;
}

// ---- 256x256 8-phase BT GEMM, bf16 MFMA 16x16x32 -------------------------
// A: [M,K] row-major bf16.  B: [N,K] row-major bf16 (B^T of math B).
// 8 waves (2M x 4N), per-wave 128x64 C block, acc[8][4], BK=64, dbuf LDS 128KB.
// LDS layout per tile: [256 rows][64 cols], 16B chunk c of row r stored at
// position p=(c+r)&7 (rotation swizzle -> 2-way banks = free). Staging keeps
// LDS dest linear (global_load_lds constraint) and pre-rotates the per-lane
// GLOBAL source chunk: c = ((lane&7)-(lane>>3))&7 (uniform across h/q since
// their row offsets are multiples of 8).
// Schedule per iteration (2 K-tiles t,t+1; buf0=even, buf1=odd):
//   ph1 Q00(buf0) reads A0-3,B0-1 | stage (t+1).A0 -> buf1
//   ph2 Q01(buf0) reads B2-3      | stage (t+1).A1
//   ph3 Q11(buf0) reads A4-7      | stage (t+2).B0 -> buf0 (B reads retired ph2)
//   ph4 Q10(buf0) no reads        | stage (t+2).B1 ; vmcnt(4)
//   ph5 Q00(buf1)                 | stage (t+2).A0 -> buf0 (A reads retired ph3)
//   ph6 Q01(buf1)                 | stage (t+2).A1
//   ph7 Q11(buf1)                 | stage (t+3).B0 -> buf1 (B reads retired ph6)
//   ph8 Q10(buf1)                 | stage (t+3).B1 ; vmcnt(4)
// Every stage is issued after the barrier that retires the previous reads of
// its target region -> race-free; vmcnt(4) leaves exactly the 2 newest
// half-tiles in flight, so the tile read next is always fully landed.
// EPI==0: C = gelu_exact(acc + bias[n]) -> bf16 Cout [M,N]
// EPI==1: C = acc*scale[n] + bias[n]    -> fp32 Cout [M,N]
template <int EPI>
__global__ void __launch_bounds__(512, 2)
gemm256(const __bf16* __restrict__ A, const __bf16* __restrict__ B,
        const float* __restrict__ bias, const float* __restrict__ scale,
        void* __restrict__ Cout, int M, int N, int K)
{
  __shared__ __attribute__((aligned(16))) __bf16 sA[2 * 256 * 64];  // 64 KB
  __shared__ __attribute__((aligned(16))) __bf16 sB[2 * 256 * 64];  // 64 KB

  const int tid  = threadIdx.x;
  const int wave = tid >> 6;
  const int lane = tid & 63;

  // --- bijective XCD-aware block swizzle (m204)
  const int nwg  = (int)(gridDim.x * gridDim.y);
  const int orig = (int)(blockIdx.y * gridDim.x + blockIdx.x);
  const int q8 = nwg >> 3, r8 = nwg & 7;
  const int xcd = orig & 7, loc = orig >> 3;
  const int wg = (xcd < r8 ? xcd * (q8 + 1) : r8 * (q8 + 1) + (xcd - r8) * q8) + loc;
  const int bx = wg % (int)gridDim.x, by = wg / (int)gridDim.x;
  const int bm = by << 8, bn = bx << 8;

  // --- staging lane constants: per issue, wave covers 8 rows (1024B), lane
  // covers 16B at row (wave*8 + l>>3), stored position p = l&7.
  const int srow = (wave << 3) + (lane >> 3);
  const int c8   = ((lane & 7) - (lane >> 3)) & 7;   // pre-rotated source chunk
  const __bf16* pA = A + (size_t)(bm + srow) * K + (c8 << 3);
  const __bf16* pB = B + (size_t)(bn + srow) * K + (c8 << 3);
  const int swv = wave << 9;                          // wave*8 rows * 64 elems

  // --- fragment lane constants
  const int fl = lane & 15, kq = lane >> 4;
  const int wm = wave >> 2, wn = wave & 3;            // 2M x 4N wave grid
  const int rAo = ((wm << 7) + fl) << 6;              // (wm*128+fl)*64
  const int rBo = ((wn << 6) + fl) << 6;              // (wn*64 +fl)*64
  const int pk0 = ((kq + fl) & 7) << 3;               // rotated pos, ks=0
  const int pk1 = ((kq + fl + 4) & 7) << 3;           // rotated pos, ks=1

  f32x4 acc[8][4] = {};
  bf16x8 af[4][2], bf0[2][2], bf1[2][2];

  const int nt = K >> 6;                              // K-tiles (even: K%128==0)

#define STG_HA(buf, h, kt) do {                                                \
    gload_lds16(pA + (size_t)((h) * 128) * K + (size_t)(kt) * 64,              \
                sA + ((buf) << 14) + (h) * 8192 + swv);                        \
    gload_lds16(pA + (size_t)((h) * 128 + 64) * K + (size_t)(kt) * 64,         \
                sA + ((buf) << 14) + (h) * 8192 + 4096 + swv);                 \
  } while (0)
#define STG_HB(buf, h, kt) do {                                                \
    gload_lds16(pB + (size_t)((h) * 128) * K + (size_t)(kt) * 64,              \
                sB + ((buf) << 14) + (h) * 8192 + swv);                        \
    gload_lds16(pB + (size_t)((h) * 128 + 64) * K + (size_t)(kt) * 64,         \
                sB + ((buf) << 14) + (h) * 8192 + 4096 + swv);                 \
  } while (0)
#define LDAF(buf, ib) do { _Pragma("unroll")                                   \
    for (int i = 0; i < 4; ++i) {                                              \
      af[i][0] = *(const bf16x8*)(sA + ((buf) << 14) + rAo + ((ib) + i) * 1024 + pk0); \
      af[i][1] = *(const bf16x8*)(sA + ((buf) << 14) + rAo + ((ib) + i) * 1024 + pk1); \
    } } while (0)
#define LDBF(dst, buf, jb) do { _Pragma("unroll")                              \
    for (int j = 0; j < 2; ++j) {                                              \
      dst[j][0] = *(const bf16x8*)(sB + ((buf) << 14) + rBo + ((jb) + j) * 1024 + pk0); \
      dst[j][1] = *(const bf16x8*)(sB + ((buf) << 14) + rBo + ((jb) + j) * 1024 + pk1); \
    } } while (0)
#define MMQ(ib, jb, bfr) do { _Pragma("unroll")                                \
    for (int i = 0; i < 4; ++i) { _Pragma("unroll")                            \
      for (int j = 0; j < 2; ++j) {                                            \
        acc[(ib)+i][(jb)+j] = __builtin_amdgcn_mfma_f32_16x16x32_bf16(af[i][0], bfr[j][0], acc[(ib)+i][(jb)+j], 0, 0, 0); \
        acc[(ib)+i][(jb)+j] = __builtin_amdgcn_mfma_f32_16x16x32_bf16(af[i][1], bfr[j][1], acc[(ib)+i][(jb)+j], 0, 0, 0); \
      } } } while (0)

  // --- prologue: tile0 (all 4 halves) -> buf0; tile1 B-halves -> buf1.
  // vmcnt(4) leaves only tile1's B halves in flight -> tile0 fully landed.
  STG_HA(0, 0, 0); STG_HA(0, 1, 0);
  STG_HB(0, 0, 0); STG_HB(0, 1, 0);
  { const int t1 = nt > 1 ? 1 : 0; STG_HB(1, 0, t1); STG_HB(1, 1, t1); }
  vm4_();
  barrier_();

#pragma unroll 1
  for (int t = 0; t < nt; t += 2) {
    const int tA1 = t + 1;                                  // always < nt (nt even)
    const int tN2 = (t + 2 < nt) ? t + 2 : nt - 1;          // clamped restage = benign
    const int tN3 = (t + 3 < nt) ? t + 3 : nt - 1;

    // phase 1: Q00 buf0
    LDAF(0, 0); LDBF(bf0, 0, 0);
    STG_HA(1, 0, tA1);
    barrier_(); lgkm0_();
    __builtin_amdgcn_s_setprio(1); MMQ(0, 0, bf0); __builtin_amdgcn_s_setprio(0);
    barrier_();
    // phase 2: Q01 buf0
    LDBF(bf1, 0, 2);
    STG_HA(1, 1, tA1);
    barrier_(); lgkm0_();
    __builtin_amdgcn_s_setprio(1); MMQ(0, 2, bf1); __builtin_amdgcn_s_setprio(0);
    barrier_();
    // phase 3: Q11 buf0
    LDAF(0, 4);
    STG_HB(0, 0, tN2);
    barrier_(); lgkm0_();
    __builtin_amdgcn_s_setprio(1); MMQ(4, 2, bf1); __builtin_amdgcn_s_setprio(0);
    barrier_();
    // phase 4: Q10 buf0 (frags cached)
    STG_HB(0, 1, tN2);
    vm4_();
    barrier_(); lgkm0_();
    __builtin_amdgcn_s_setprio(1); MMQ(4, 0, bf0); __builtin_amdgcn_s_setprio(0);
    barrier_();
    // phase 5: Q00 buf1
    LDAF(1, 0); LDBF(bf0, 1, 0);
    STG_HA(0, 0, tN2);
    barrier_(); lgkm0_();
    __builtin_amdgcn_s_setprio(1); MMQ(0, 0, bf0); __builtin_amdgcn_s_setprio(0);
    barrier_();
    // phase 6: Q01 buf1
    LDBF(bf1, 1, 2);
    STG_HA(0, 1, tN2);
    barrier_(); lgkm0_();
    __builtin_amdgcn_s_setprio(1); MMQ(0, 2, bf1); __builtin_amdgcn_s_setprio(0);
    barrier_();
    // phase 7: Q11 buf1
    LDAF(1, 4);
    STG_HB(1, 0, tN3);
    barrier_(); lgkm0_();
    __builtin_amdgcn_s_setprio(1); MMQ(4, 2, bf1); __builtin_amdgcn_s_setprio(0);
    barrier_();
    // phase 8: Q10 buf1
    STG_HB(1, 1, tN3);
    vm4_();
    barrier_(); lgkm0_();
    __builtin_amdgcn_s_setprio(1); MMQ(4, 0, bf0); __builtin_amdgcn_s_setprio(0);
    barrier_();
  }

#undef STG_HA
#undef STG_HB
#undef LDAF
#undef LDBF
#undef MMQ

  // --- epilogue: C/D layout col = lane&15 (N dim), row = (lane>>4)*4 + reg
  if (EPI == 0) {
    __bf16* H = (__bf16*)Cout;
#pragma unroll
    for (int jj = 0; jj < 4; ++jj) {
      const int col = bn + (wn << 6) + (jj << 4) + fl;
      const float bvl = bias[col];
#pragma unroll
      for (int ii = 0; ii < 8; ++ii) {
        const int row0 = bm + (wm << 7) + (ii << 4) + (kq << 2);
#pragma unroll
        for (int r = 0; r < 4; ++r) {
          float v = acc[ii][jj][r] + bvl;
          v = 0.5f * v * (1.0f + erff(v * 0.70710678118654752f));  // exact GELU
          H[(size_t)(row0 + r) * N + col] = (__bf16)v;
        }
      }
    }
  } else {
    float* O = (float*)Cout;
#pragma unroll
    for (int jj = 0; jj < 4; ++jj) {
      const int col = bn + (wn << 6) + (jj << 4) + fl;
      const float sv  = scale[col];
      const float bvl = bias[col];
#pragma unroll
      for (int ii = 0; ii < 8; ++ii) {
        const int row0 = bm + (wm << 7) + (ii << 4) + (kq << 2);
#pragma unroll
        for (int r = 0; r < 4; ++r) {
          O[(size_t)(row0 + r) * N + col] = acc[ii][jj][r] * sv + bvl;
        }
      }
    }
  }
}

// ---- driver --------------------------------------------------------------
extern "C" void kernel_launch(void* const* d_in, const int* in_sizes, int n_in,
                              void* d_out, int out_size, void* d_ws, size_t ws_size,
                              hipStream_t stream)
{
  const float* x   = (const float*)d_in[0];   // [M, D] (flattened B,S)
  const float* wup = (const float*)d_in[1];   // [DI, D]  == [N,K] for GEMM1
  const float* bup = (const float*)d_in[2];   // [DI]
  const int*   wdq = (const int*)d_in[3];     // [D, DI]  == [N,K] for GEMM2
  const float* wds = (const float*)d_in[4];   // [D]
  const float* bdn = (const float*)d_in[5];   // [D]
  float* out = (float*)d_out;

  const int  DI = in_sizes[2];                // 8192
  const int  D  = in_sizes[4];                // 2048
  const long M  = (long)in_sizes[0] / D;      // 16384

  // workspace layout (all bf16): xb[M*D] | wub[DI*D] | wdb[D*DI] | hb[CH*DI]
  __bf16* xb  = (__bf16*)d_ws;
  __bf16* wub = xb  + (size_t)M * D;
  __bf16* wdb = wub + (size_t)DI * D;
  __bf16* hb  = wdb + (size_t)D * DI;

  const size_t fixed = 2ull * ((size_t)M * D + 2ull * (size_t)DI * D);
  long CH = M;                                // M-chunk size (multiple of 256)
  while (CH > 256 && fixed + 2ull * (size_t)CH * DI > ws_size) CH >>= 1;

  long n4;
  n4 = (long)M * D / 4;
  cvt_f32_bf16<<<(n4 + 255) / 256, 256, 0, stream>>>((const float4*)x, (bf16x4*)xb, n4);
  n4 = (long)DI * D / 4;
  cvt_f32_bf16<<<(n4 + 255) / 256, 256, 0, stream>>>((const float4*)wup, (bf16x4*)wub, n4);
  n4 = (long)D * DI / 4;
  cvt_i32_bf16<<<(n4 + 255) / 256, 256, 0, stream>>>((const int4*)wdq, (bf16x4*)wdb, n4);

  for (long m0 = 0; m0 < M; m0 += CH) {
    dim3 g1(DI / 256, (unsigned)(CH / 256));
    gemm256<0><<<g1, dim3(512), 0, stream>>>(xb + m0 * D, wub, bup, nullptr, hb,
                                             (int)CH, DI, D);
    dim3 g2(D / 256, (unsigned)(CH / 256));
    gemm256<1><<<g2, dim3(512), 0, stream>>>(hb, wdb, bdn, wds, out + m0 * D,
                                             (int)CH, D, DI);
  }
}